// Round 13
// baseline (618.452 us; speedup 1.0000x reference)
//
#include <hip/hip_runtime.h>
#include <hip/hip_fp16.h>
#include <hip/hip_cooperative_groups.h>

namespace cg = cooperative_groups;

#define N_NODES 100000
#define N_EDGES 1600000
// coarse buckets: 1024 nodes, bucket = dst >> 10
#define NCB 98
#define CAPC 17500          // mean 16327, sigma ~127 -> +9 sigma
// fine buckets: 64 nodes, 16 per coarse
#define BK 64
#define NBF 1563            // ceil(N/64)
#define CAPF 1408           // mean 1024, sigma ~32 -> +12 sigma
#define P1_CHUNK 2048
#define NCH 782             // ceil(E / P1_CHUNK)

__device__ __forceinline__ __half2 h2of(const float4& v, int c) {
    return reinterpret_cast<const __half2*>(&v)[c];
}

// 4-lane gather: lane owns channels 8l..8l+7, 16B loads, sentinel-padded tail.
__device__ __forceinline__ void gatherRow4(const int* __restrict__ srcSorted,
                                           const float4* __restrict__ P,
                                           int beg, int end, int l,
                                           float* __restrict__ acc /*[8]*/) {
    for (int base = beg; base < end; base += 8) {
        int i0 = base + l, i1 = base + 4 + l;
        int sA = (i0 < end) ? srcSorted[i0] : N_NODES;
        int sB = (i1 < end) ? srcSorted[i1] : N_NODES;
        float4 v0 = P[__shfl(sA, 0, 4) * 4 + l];
        float4 v1 = P[__shfl(sA, 1, 4) * 4 + l];
        float4 v2 = P[__shfl(sA, 2, 4) * 4 + l];
        float4 v3 = P[__shfl(sA, 3, 4) * 4 + l];
        float4 v4 = P[__shfl(sB, 0, 4) * 4 + l];
        float4 v5 = P[__shfl(sB, 1, 4) * 4 + l];
        float4 v6 = P[__shfl(sB, 2, 4) * 4 + l];
        float4 v7 = P[__shfl(sB, 3, 4) * 4 + l];
#pragma unroll
        for (int c = 0; c < 4; ++c) {
            __half2 s01 = __hadd2(h2of(v0, c), h2of(v1, c));
            __half2 s23 = __hadd2(h2of(v2, c), h2of(v3, c));
            __half2 s45 = __hadd2(h2of(v4, c), h2of(v5, c));
            __half2 s67 = __hadd2(h2of(v6, c), h2of(v7, c));
            __half2 sum = __hadd2(__hadd2(s01, s23), __hadd2(s45, s67));
            float2 f = __half22float2(sum);
            acc[2 * c]     += f.x;
            acc[2 * c + 1] += f.y;
        }
    }
}

// ================= fused persistent cooperative kernel =================
__global__ __launch_bounds__(256) void k_all(
    const float* __restrict__ x,
    const int* __restrict__ srcE,
    const int* __restrict__ dstE,
    const float* __restrict__ W1,
    const float* __restrict__ b1,
    const float* __restrict__ Wmu,
    const float* __restrict__ bmu,
    const float* __restrict__ Wlv,
    const float* __restrict__ blv,
    int* __restrict__ cursor1,
    int* __restrict__ cursor2,
    int* __restrict__ rowBeg,
    int* __restrict__ rowEnd,
    float* __restrict__ dinv,
    unsigned* __restrict__ packed1,
    unsigned* __restrict__ packed2,
    int* __restrict__ srcSorted,
    __half* __restrict__ p1,
    __half* __restrict__ p2,
    float* __restrict__ out)
{
    cg::grid_group grid = cg::this_grid();
    __shared__ int bh[NCB];
    __shared__ int base[NCB];
    __shared__ int cnt[BK];
    __shared__ int scn[BK];
    __shared__ int cur[BK];
    __shared__ float sW[1024];
    __shared__ float sB[32];
    int t = threadIdx.x;
    int blk = blockIdx.x;
    int G = gridDim.x;

    // ---- phase A: init bucket cursors (grid-stride) ----
    for (int i = blk * 256 + t; i < NBF; i += G * 256) {
        cursor2[i] = i * CAPF;
        if (i < NCB) cursor1[i] = i * CAPC;
    }
    grid.sync();

    // ---- phase B: coarse partition, grid-stride over 2048-edge chunks ----
    // packed1 entry: (dstLow10 << 17) | src17
    for (int u = blk; u < NCH; u += G) {
        __syncthreads();
        if (t < NCB) bh[t] = 0;
        __syncthreads();
        int e0 = u * P1_CHUNK;
        int e1 = e0 + P1_CHUNK; if (e1 > N_EDGES) e1 = N_EDGES;
        for (int e = e0 + t; e < e1; e += 256)
            atomicAdd(&bh[((unsigned)dstE[e]) >> 10], 1);
        __syncthreads();
        if (t < NCB) {
            int c = bh[t];
            base[t] = (c > 0) ? atomicAdd(&cursor1[t], c) : 0;
            bh[t] = 0;   // reuse as rank counter
        }
        __syncthreads();
        for (int e = e0 + t; e < e1; e += 256) {
            unsigned d = (unsigned)dstE[e];
            int b = d >> 10;
            int r = atomicAdd(&bh[b], 1);
            int pos = base[b] + r;
            if (pos < (b + 1) * CAPC)   // statistically impossible overflow guard
                packed1[pos] = ((d & 1023u) << 17) | (unsigned)srcE[e];
        }
    }
    grid.sync();

    // ---- phase C: refine coarse -> fine buckets (98*16 = 1568 units) ----
    // packed2 entry: (dstLow6 << 17) | src17
    for (int u = blk; u < NCB * 16; u += G) {
        __syncthreads();
        int c = u >> 4;
        int k = u & 15;
        int cc = cursor1[c] - c * CAPC; if (cc > CAPC) cc = CAPC;
        int s0 = c * CAPC + (k * cc) / 16;
        int s1 = c * CAPC + ((k + 1) * cc) / 16;
        if (t < 16) bh[t] = 0;
        __syncthreads();
        for (int i = s0 + t; i < s1; i += 256)
            atomicAdd(&bh[(packed1[i] >> 17) >> 6], 1);
        __syncthreads();
        if (t < 16) {
            int c2 = bh[t];
            int fb = c * 16 + t;   // fb >= NBF only when c2==0 (tail coarse)
            base[t] = (c2 > 0) ? atomicAdd(&cursor2[fb], c2) : 0;
            bh[t] = 0;
        }
        __syncthreads();
        for (int i = s0 + t; i < s1; i += 256) {
            unsigned pk = packed1[i];
            unsigned dl = pk >> 17;
            int f = dl >> 6;
            int r = atomicAdd(&bh[f], 1);
            int pos = base[f] + r;
            int fb = c * 16 + f;
            if (pos < (fb + 1) * CAPF)
                packed2[pos] = ((dl & 63u) << 17) | (pk & 0x1FFFFu);
        }
    }
    grid.sync();

    // ---- phase D: per-fine-bucket CSR + dinv + p1 = dinv*(x@W1) + sentinel ----
    for (int i = t; i < 1024; i += 256) sW[i] = W1[i];
    for (int u = blk; u < NBF; u += G) {
        __syncthreads();
        if (t < BK) cnt[t] = 0;
        __syncthreads();
        int seg0 = u * CAPF;
        int cc = cursor2[u] - seg0; if (cc > CAPF) cc = CAPF;
        int segEnd = seg0 + cc;
        for (int i = seg0 + t; i < segEnd; i += 256)
            atomicAdd(&cnt[packed2[i] >> 17], 1);
        __syncthreads();
        int v = (t < BK) ? cnt[t] : 0;
        if (t < BK) scn[t] = v;
        __syncthreads();
        for (int off = 1; off < BK; off <<= 1) {
            int uu = (t < BK && t >= off) ? scn[t - off] : 0;
            __syncthreads();
            if (t < BK) scn[t] += uu;
            __syncthreads();
        }
        int node = u * BK + t;
        if (t < BK) {
            int start = seg0 + scn[t] - v;
            if (node < N_NODES) {
                rowBeg[node] = start;
                rowEnd[node] = start + v;
                dinv[node] = rsqrtf((float)(v + 1));   // +1 = self loop
            }
            cur[t] = start;
        }
        __syncthreads();
        for (int i = seg0 + t; i < segEnd; i += 256) {
            unsigned pk = packed2[i];
            int pos = atomicAdd(&cur[pk >> 17], 1);
            srcSorted[pos] = (int)(pk & 0x1FFFFu);
        }
        int lane = t & 31;
        for (int r = (t >> 5); r < BK; r += 8) {
            int nd = u * BK + r;
            if (nd > N_NODES) break;
            if (nd == N_NODES) {                      // sentinel zero row
                p1[nd * 32 + lane] = __float2half(0.f);
                continue;
            }
            float xv = x[nd * 32 + lane];
            float a = 0.f;
#pragma unroll
            for (int k = 0; k < 32; ++k) {
                float xk = __shfl(xv, k, 32);
                a += xk * sW[k * 32 + lane];
            }
            float di = rsqrtf((float)(cnt[r] + 1));
            p1[nd * 32 + lane] = __float2half(di * a);
        }
    }
    grid.sync();

    // ---- phase E: gather layer 1 + relu + layer-2 matmul (4 lanes/node) ----
    for (int i = t; i < 1024; i += 256) {
        int k = i >> 5, oc = i & 31;
        sW[i] = (oc < 16) ? Wmu[k * 16 + oc] : Wlv[k * 16 + (oc - 16)];
    }
    if (t < 32) sB[t] = b1[t];
    __syncthreads();
    {
        int l = t & 3;
        const float4* P = (const float4*)p1;
        const float4* W4 = (const float4*)sW;
        for (int u = blk; u < NBF; u += G) {
            int node = u * 64 + (t >> 2);
            if (node > N_NODES) continue;
            if (node == N_NODES) {                    // sentinel zero row of p2
                ((float4*)p2)[node * 4 + l] = make_float4(0.f, 0.f, 0.f, 0.f);
                continue;
            }
            float acc[8] = {0.f, 0.f, 0.f, 0.f, 0.f, 0.f, 0.f, 0.f};
            gatherRow4(srcSorted, P, rowBeg[node], rowEnd[node], l, acc);
            float di = dinv[node];
            float4 ps = P[node * 4 + l];              // self loop analytic
            float h[8];
#pragma unroll
            for (int c = 0; c < 4; ++c) {
                float2 f = __half22float2(h2of(ps, c));
                h[2 * c]     = fmaxf(di * (acc[2 * c]     + f.x) + sB[8 * l + 2 * c],     0.f);
                h[2 * c + 1] = fmaxf(di * (acc[2 * c + 1] + f.y) + sB[8 * l + 2 * c + 1], 0.f);
            }
            float o[8] = {0.f, 0.f, 0.f, 0.f, 0.f, 0.f, 0.f, 0.f};
#pragma unroll
            for (int m = 0; m < 4; ++m) {
#pragma unroll
                for (int j = 0; j < 8; ++j) {
                    float hk = __shfl(h[j], m, 4);    // channel k = 8m+j
                    int k = 8 * m + j;
                    float4 wa = W4[k * 8 + 2 * l];
                    float4 wb = W4[k * 8 + 2 * l + 1];
                    o[0] += hk * wa.x; o[1] += hk * wa.y; o[2] += hk * wa.z; o[3] += hk * wa.w;
                    o[4] += hk * wb.x; o[5] += hk * wb.y; o[6] += hk * wb.z; o[7] += hk * wb.w;
                }
            }
            __half2 r0 = __floats2half2_rn(di * o[0], di * o[1]);
            __half2 r1 = __floats2half2_rn(di * o[2], di * o[3]);
            __half2 r2 = __floats2half2_rn(di * o[4], di * o[5]);
            __half2 r3 = __floats2half2_rn(di * o[6], di * o[7]);
            float4 st;
            st.x = *reinterpret_cast<float*>(&r0);
            st.y = *reinterpret_cast<float*>(&r1);
            st.z = *reinterpret_cast<float*>(&r2);
            st.w = *reinterpret_cast<float*>(&r3);
            ((float4*)p2)[node * 4 + l] = st;
        }
    }
    grid.sync();

    // ---- phase F: gather layer 2 + mu/logvar epilogue (4 lanes/node) ----
    if (t < 32) sB[t] = (t < 16) ? bmu[t] : blv[t - 16];
    __syncthreads();
    {
        int l = t & 3;
        const float4* P = (const float4*)p2;
        for (int u = blk; u < NBF; u += G) {
            int node = u * 64 + (t >> 2);
            if (node >= N_NODES) continue;
            float acc[8] = {0.f, 0.f, 0.f, 0.f, 0.f, 0.f, 0.f, 0.f};
            gatherRow4(srcSorted, P, rowBeg[node], rowEnd[node], l, acc);
            float di = dinv[node];
            float4 ps = P[node * 4 + l];
            float v[8];
#pragma unroll
            for (int c = 0; c < 4; ++c) {
                float2 f = __half22float2(h2of(ps, c));
                v[2 * c]     = di * (acc[2 * c]     + f.x) + sB[8 * l + 2 * c];
                v[2 * c + 1] = di * (acc[2 * c + 1] + f.y) + sB[8 * l + 2 * c + 1];
            }
            float4 o0 = make_float4(v[0], v[1], v[2], v[3]);
            float4 o1 = make_float4(v[4], v[5], v[6], v[7]);
            float4* dst4 = (l < 2) ? (float4*)out
                                   : (float4*)(out + (size_t)N_NODES * 16);
            int b4 = node * 4 + (l & 1) * 2;
            dst4[b4]     = o0;
            dst4[b4 + 1] = o1;
        }
    }
}

// ================= fallback: proven R11 6-kernel path =================
__global__ __launch_bounds__(1024) void k_binit(int* __restrict__ cursor1,
                                                int* __restrict__ cursor2) {
    int i = blockIdx.x * 1024 + threadIdx.x;
    if (i < NCB) cursor1[i] = i * CAPC;
    if (i < NBF) cursor2[i] = i * CAPF;
}

__global__ __launch_bounds__(256) void k_part1(const int* __restrict__ src,
                                               const int* __restrict__ dst,
                                               int* __restrict__ cursor1,
                                               unsigned* __restrict__ packed1) {
    __shared__ int bh[NCB];
    __shared__ int base[NCB];
    int t = threadIdx.x;
    if (t < NCB) bh[t] = 0;
    __syncthreads();
    int e0 = blockIdx.x * P1_CHUNK;
    int e1 = e0 + P1_CHUNK; if (e1 > N_EDGES) e1 = N_EDGES;
    for (int e = e0 + t; e < e1; e += 256)
        atomicAdd(&bh[((unsigned)dst[e]) >> 10], 1);
    __syncthreads();
    if (t < NCB) {
        int c = bh[t];
        base[t] = (c > 0) ? atomicAdd(&cursor1[t], c) : 0;
        bh[t] = 0;
    }
    __syncthreads();
    for (int e = e0 + t; e < e1; e += 256) {
        unsigned d = (unsigned)dst[e];
        int b = d >> 10;
        int r = atomicAdd(&bh[b], 1);
        int pos = base[b] + r;
        if (pos < (b + 1) * CAPC)
            packed1[pos] = ((d & 1023u) << 17) | (unsigned)src[e];
    }
}

__global__ __launch_bounds__(256) void k_part2(const unsigned* __restrict__ packed1,
                                               const int* __restrict__ cursor1,
                                               int* __restrict__ cursor2,
                                               unsigned* __restrict__ packed2) {
    __shared__ int bh[16];
    __shared__ int base[16];
    int t = threadIdx.x;
    int c = blockIdx.x >> 4;
    int k = blockIdx.x & 15;
    int cc = cursor1[c] - c * CAPC; if (cc > CAPC) cc = CAPC;
    int s0 = c * CAPC + (k * cc) / 16;
    int s1 = c * CAPC + ((k + 1) * cc) / 16;
    if (t < 16) bh[t] = 0;
    __syncthreads();
    for (int i = s0 + t; i < s1; i += 256)
        atomicAdd(&bh[(packed1[i] >> 17) >> 6], 1);
    __syncthreads();
    if (t < 16) {
        int cnt = bh[t];
        int fb = c * 16 + t;
        base[t] = (cnt > 0) ? atomicAdd(&cursor2[fb], cnt) : 0;
        bh[t] = 0;
    }
    __syncthreads();
    for (int i = s0 + t; i < s1; i += 256) {
        unsigned pk = packed1[i];
        unsigned dl = pk >> 17;
        int f = dl >> 6;
        int r = atomicAdd(&bh[f], 1);
        int pos = base[f] + r;
        int fb = c * 16 + f;
        if (pos < (fb + 1) * CAPF)
            packed2[pos] = ((dl & 63u) << 17) | (pk & 0x1FFFFu);
    }
}

__global__ __launch_bounds__(256) void k_csrx(const unsigned* __restrict__ packed2,
                                              const int* __restrict__ cursor2,
                                              const float* __restrict__ x,
                                              const float* __restrict__ W1,
                                              int* __restrict__ rowBeg,
                                              int* __restrict__ rowEnd,
                                              float* __restrict__ dinv,
                                              int* __restrict__ srcSorted,
                                              __half* __restrict__ p1) {
    __shared__ int cnt[BK];
    __shared__ int scn[BK];
    __shared__ int cur[BK];
    __shared__ float sW[1024];
    int t = threadIdx.x;
    int b = blockIdx.x;
    int seg0 = b * CAPF;
    int cc = cursor2[b] - seg0; if (cc > CAPF) cc = CAPF;
    int segEnd = seg0 + cc;
    if (t < BK) cnt[t] = 0;
    for (int i = t; i < 1024; i += 256) sW[i] = W1[i];
    __syncthreads();
    for (int i = seg0 + t; i < segEnd; i += 256)
        atomicAdd(&cnt[packed2[i] >> 17], 1);
    __syncthreads();
    int v = (t < BK) ? cnt[t] : 0;
    if (t < BK) scn[t] = v;
    __syncthreads();
    for (int off = 1; off < BK; off <<= 1) {
        int u = (t < BK && t >= off) ? scn[t - off] : 0;
        __syncthreads();
        if (t < BK) scn[t] += u;
        __syncthreads();
    }
    int node = b * BK + t;
    if (t < BK) {
        int start = seg0 + scn[t] - v;
        if (node < N_NODES) {
            rowBeg[node] = start;
            rowEnd[node] = start + v;
            dinv[node] = rsqrtf((float)(v + 1));
        }
        cur[t] = start;
    }
    __syncthreads();
    for (int i = seg0 + t; i < segEnd; i += 256) {
        unsigned pk = packed2[i];
        int pos = atomicAdd(&cur[pk >> 17], 1);
        srcSorted[pos] = (int)(pk & 0x1FFFFu);
    }
    int lane = t & 31;
    for (int r = (t >> 5); r < BK; r += 8) {
        int nd = b * BK + r;
        if (nd > N_NODES) break;
        if (nd == N_NODES) {
            p1[nd * 32 + lane] = __float2half(0.f);
            continue;
        }
        float xv = x[nd * 32 + lane];
        float a = 0.f;
#pragma unroll
        for (int k = 0; k < 32; ++k) {
            float xk = __shfl(xv, k, 32);
            a += xk * sW[k * 32 + lane];
        }
        float di = rsqrtf((float)(cnt[r] + 1));
        p1[nd * 32 + lane] = __float2half(di * a);
    }
}

__global__ __launch_bounds__(256) void k_gx2(const int* __restrict__ rowBeg,
                                             const int* __restrict__ rowEnd,
                                             const int* __restrict__ srcSorted,
                                             const __half* __restrict__ p1,
                                             const float* __restrict__ dinv,
                                             const float* __restrict__ b1,
                                             const float* __restrict__ Wmu,
                                             const float* __restrict__ Wlv,
                                             __half* __restrict__ p2) {
    __shared__ float sW[1024];
    __shared__ float sB[32];
    int t = threadIdx.x;
    for (int i = t; i < 1024; i += 256) {
        int k = i >> 5, oc = i & 31;
        sW[i] = (oc < 16) ? Wmu[k * 16 + oc] : Wlv[k * 16 + (oc - 16)];
    }
    if (t < 32) sB[t] = b1[t];
    __syncthreads();
    int l = t & 3;
    int node = blockIdx.x * 64 + (t >> 2);
    if (node > N_NODES) return;
    const float4* P = (const float4*)p1;
    if (node == N_NODES) {
        ((float4*)p2)[node * 4 + l] = make_float4(0.f, 0.f, 0.f, 0.f);
        return;
    }
    float acc[8] = {0.f, 0.f, 0.f, 0.f, 0.f, 0.f, 0.f, 0.f};
    gatherRow4(srcSorted, P, rowBeg[node], rowEnd[node], l, acc);
    float di = dinv[node];
    float4 ps = P[node * 4 + l];
    float h[8];
#pragma unroll
    for (int c = 0; c < 4; ++c) {
        float2 f = __half22float2(h2of(ps, c));
        h[2 * c]     = fmaxf(di * (acc[2 * c]     + f.x) + sB[8 * l + 2 * c],     0.f);
        h[2 * c + 1] = fmaxf(di * (acc[2 * c + 1] + f.y) + sB[8 * l + 2 * c + 1], 0.f);
    }
    float o[8] = {0.f, 0.f, 0.f, 0.f, 0.f, 0.f, 0.f, 0.f};
    const float4* W4 = (const float4*)sW;
#pragma unroll
    for (int m = 0; m < 4; ++m) {
#pragma unroll
        for (int j = 0; j < 8; ++j) {
            float hk = __shfl(h[j], m, 4);
            int k = 8 * m + j;
            float4 wa = W4[k * 8 + 2 * l];
            float4 wb = W4[k * 8 + 2 * l + 1];
            o[0] += hk * wa.x; o[1] += hk * wa.y; o[2] += hk * wa.z; o[3] += hk * wa.w;
            o[4] += hk * wb.x; o[5] += hk * wb.y; o[6] += hk * wb.z; o[7] += hk * wb.w;
        }
    }
    __half2 r0 = __floats2half2_rn(di * o[0], di * o[1]);
    __half2 r1 = __floats2half2_rn(di * o[2], di * o[3]);
    __half2 r2 = __floats2half2_rn(di * o[4], di * o[5]);
    __half2 r3 = __floats2half2_rn(di * o[6], di * o[7]);
    float4 st;
    st.x = *reinterpret_cast<float*>(&r0);
    st.y = *reinterpret_cast<float*>(&r1);
    st.z = *reinterpret_cast<float*>(&r2);
    st.w = *reinterpret_cast<float*>(&r3);
    ((float4*)p2)[node * 4 + l] = st;
}

__global__ __launch_bounds__(256) void k_gfin(const int* __restrict__ rowBeg,
                                              const int* __restrict__ rowEnd,
                                              const int* __restrict__ srcSorted,
                                              const __half* __restrict__ p2,
                                              const float* __restrict__ dinv,
                                              const float* __restrict__ bmu,
                                              const float* __restrict__ blv,
                                              float* __restrict__ out) {
    __shared__ float sB[32];
    int t = threadIdx.x;
    if (t < 32) sB[t] = (t < 16) ? bmu[t] : blv[t - 16];
    __syncthreads();
    int l = t & 3;
    int node = blockIdx.x * 64 + (t >> 2);
    if (node >= N_NODES) return;
    const float4* P = (const float4*)p2;
    float acc[8] = {0.f, 0.f, 0.f, 0.f, 0.f, 0.f, 0.f, 0.f};
    gatherRow4(srcSorted, P, rowBeg[node], rowEnd[node], l, acc);
    float di = dinv[node];
    float4 ps = P[node * 4 + l];
    float v[8];
#pragma unroll
    for (int c = 0; c < 4; ++c) {
        float2 f = __half22float2(h2of(ps, c));
        v[2 * c]     = di * (acc[2 * c]     + f.x) + sB[8 * l + 2 * c];
        v[2 * c + 1] = di * (acc[2 * c + 1] + f.y) + sB[8 * l + 2 * c + 1];
    }
    float4 o0 = make_float4(v[0], v[1], v[2], v[3]);
    float4 o1 = make_float4(v[4], v[5], v[6], v[7]);
    float4* dst4 = (l < 2) ? (float4*)out
                           : (float4*)(out + (size_t)N_NODES * 16);
    int b4 = node * 4 + (l & 1) * 2;
    dst4[b4]     = o0;
    dst4[b4 + 1] = o1;
}

extern "C" void kernel_launch(void* const* d_in, const int* in_sizes, int n_in,
                              void* d_out, int out_size, void* d_ws, size_t ws_size,
                              hipStream_t stream) {
    const float* x   = (const float*)d_in[0];
    const int*   ei  = (const int*)d_in[1];
    const float* W1  = (const float*)d_in[2];
    const float* b1  = (const float*)d_in[3];
    const float* Wmu = (const float*)d_in[4];
    const float* bmu = (const float*)d_in[5];
    const float* Wlv = (const float*)d_in[6];
    const float* blv = (const float*)d_in[7];
    float* out = (float*)d_out;

    const int* src = ei;            // edge_index[0]
    const int* dst = ei + N_EDGES;  // edge_index[1]

    size_t off = 0;
    int* cursor1 = (int*)d_ws;                          off += NCB;
    int* cursor2 = (int*)d_ws + off;                    off += NBF;
    int* rowBeg  = (int*)d_ws + off;                    off += N_NODES;
    int* rowEnd  = (int*)d_ws + off;                    off += N_NODES;
    float* dinv  = (float*)((int*)d_ws + off);          off += N_NODES;
    off = (off + 63) & ~(size_t)63;                     // 256B align
    unsigned* packed1 = (unsigned*)((int*)d_ws + off);  off += (size_t)NCB * CAPC;
    off = (off + 63) & ~(size_t)63;
    unsigned* packed2 = (unsigned*)((int*)d_ws + off);  off += (size_t)NBF * CAPF;
    off = (off + 63) & ~(size_t)63;
    int* srcSorted    = (int*)d_ws + off;
    __half* p1h       = (__half*)packed1;  // alias: packed1 dead after phase C
    __half* p2h       = (__half*)packed2;  // alias: packed2 dead after phase D

    // Occupancy-derived cooperative grid (host-side queries; capture-safe,
    // deterministic across calls).
    int dev = 0;
    (void)hipGetDevice(&dev);
    int numCU = 0;
    (void)hipDeviceGetAttribute(&numCU, hipDeviceAttributeMultiprocessorCount, dev);
    int occ = 0;
    (void)hipOccupancyMaxActiveBlocksPerMultiprocessor(&occ, (const void*)k_all, 256, 0);
    int grid = (numCU > 0 && occ > 0) ? numCU * occ : 0;
    if (grid > 1568) grid = 1568;   // no benefit beyond max phase unit count

    hipError_t err = hipErrorUnknown;
    if (grid > 0) {
        void* kargs[] = {
            (void*)&x, (void*)&src, (void*)&dst,
            (void*)&W1, (void*)&b1, (void*)&Wmu, (void*)&bmu, (void*)&Wlv, (void*)&blv,
            (void*)&cursor1, (void*)&cursor2, (void*)&rowBeg, (void*)&rowEnd, (void*)&dinv,
            (void*)&packed1, (void*)&packed2, (void*)&srcSorted,
            (void*)&p1h, (void*)&p2h, (void*)&out
        };
        err = hipLaunchCooperativeKernel((void*)k_all, dim3(grid), dim3(256),
                                         kargs, 0, stream);
    }
    if (err != hipSuccess) {
        // fallback: proven 6-kernel path (R11)
        k_binit<<<2, 1024, 0, stream>>>(cursor1, cursor2);
        k_part1<<<NCH, 256, 0, stream>>>(src, dst, cursor1, packed1);
        k_part2<<<NCB * 16, 256, 0, stream>>>(packed1, cursor1, cursor2, packed2);
        k_csrx <<<NBF, 256, 0, stream>>>(packed2, cursor2, x, W1,
                                         rowBeg, rowEnd, dinv, srcSorted, p1h);
        k_gx2  <<<NBF, 256, 0, stream>>>(rowBeg, rowEnd, srcSorted, p1h, dinv,
                                         b1, Wmu, Wlv, p2h);
        k_gfin <<<NBF, 256, 0, stream>>>(rowBeg, rowEnd, srcSorted, p2h, dinv,
                                         bmu, blv, out);
    }
}

// Round 14
// 226.637 us; speedup vs baseline: 2.7288x; 2.7288x over previous
//
#include <hip/hip_runtime.h>
#include <hip/hip_fp16.h>

#define N_NODES 100000
#define N_EDGES 1600000
// coarse buckets (partition): 1024 nodes, bucket = dst >> 10
#define NCB 98
#define CAPC 17500          // mean 16327, sigma ~127 -> +9 sigma
#define P1_CHUNK 2048
#define NCH 782             // ceil(E / P1_CHUNK)
// fine buckets (CSR): 64 nodes, 16 per coarse
#define BK 64
#define NBF 1563            // ceil(N/64)
#define CAPF 1408           // mean 1024, sigma ~32 -> +12 sigma

__device__ __forceinline__ __half2 h2of(const float4& v, int c) {
    return reinterpret_cast<const __half2*>(&v)[c];
}

// 4-lane gather: lane owns channels 8l..8l+7, 16B loads, sentinel-padded tail.
__device__ __forceinline__ void gatherRow4(const int* __restrict__ srcSorted,
                                           const float4* __restrict__ P,
                                           int beg, int end, int l,
                                           float* __restrict__ acc /*[8]*/) {
    for (int base = beg; base < end; base += 8) {
        int i0 = base + l, i1 = base + 4 + l;
        int sA = (i0 < end) ? srcSorted[i0] : N_NODES;
        int sB = (i1 < end) ? srcSorted[i1] : N_NODES;
        float4 v0 = P[__shfl(sA, 0, 4) * 4 + l];
        float4 v1 = P[__shfl(sA, 1, 4) * 4 + l];
        float4 v2 = P[__shfl(sA, 2, 4) * 4 + l];
        float4 v3 = P[__shfl(sA, 3, 4) * 4 + l];
        float4 v4 = P[__shfl(sB, 0, 4) * 4 + l];
        float4 v5 = P[__shfl(sB, 1, 4) * 4 + l];
        float4 v6 = P[__shfl(sB, 2, 4) * 4 + l];
        float4 v7 = P[__shfl(sB, 3, 4) * 4 + l];
#pragma unroll
        for (int c = 0; c < 4; ++c) {
            __half2 s01 = __hadd2(h2of(v0, c), h2of(v1, c));
            __half2 s23 = __hadd2(h2of(v2, c), h2of(v3, c));
            __half2 s45 = __hadd2(h2of(v4, c), h2of(v5, c));
            __half2 s67 = __hadd2(h2of(v6, c), h2of(v7, c));
            __half2 sum = __hadd2(__hadd2(s01, s23), __hadd2(s45, s67));
            float2 f = __half22float2(sum);
            acc[2 * c]     += f.x;
            acc[2 * c + 1] += f.y;
        }
    }
}

// ---------------- init coarse bucket cursors ----------------
__global__ __launch_bounds__(128) void k_binit(int* __restrict__ cursor1) {
    int t = threadIdx.x;
    if (t < NCB) cursor1[t] = t * CAPC;
}

// ---------------- pass 1: partition edges into 98 coarse buckets ----------------
// packed1 entry: (dstLow10 << 17) | src17
__global__ __launch_bounds__(256) void k_part1(const int* __restrict__ src,
                                               const int* __restrict__ dst,
                                               int* __restrict__ cursor1,
                                               unsigned* __restrict__ packed1) {
    __shared__ int bh[NCB];
    __shared__ int base[NCB];
    int t = threadIdx.x;
    if (t < NCB) bh[t] = 0;
    __syncthreads();
    int e0 = blockIdx.x * P1_CHUNK;
    int e1 = e0 + P1_CHUNK; if (e1 > N_EDGES) e1 = N_EDGES;
    for (int e = e0 + t; e < e1; e += 256)
        atomicAdd(&bh[((unsigned)dst[e]) >> 10], 1);
    __syncthreads();
    if (t < NCB) {
        int c = bh[t];
        base[t] = (c > 0) ? atomicAdd(&cursor1[t], c) : 0;
        bh[t] = 0;   // reuse as rank counter
    }
    __syncthreads();
    for (int e = e0 + t; e < e1; e += 256) {
        unsigned d = (unsigned)dst[e];
        int b = d >> 10;
        int r = atomicAdd(&bh[b], 1);
        int pos = base[b] + r;
        if (pos < (b + 1) * CAPC)   // statistically impossible overflow guard
            packed1[pos] = ((d & 1023u) << 17) | (unsigned)src[e];
    }
}

// ---------------- fused: fine-bucket CSR from coarse segment + dinv + xform1 ----
// Block b handles fine bucket b = coarse*16 + fl (64 nodes). It scans its
// parent coarse segment twice (filter on fl): histogram -> scan -> place.
// Also computes p1 = dinv*(x@W1) for its 64 nodes (+ sentinel zero row).
__global__ __launch_bounds__(256) void k_csrx(const unsigned* __restrict__ packed1,
                                              const int* __restrict__ cursor1,
                                              const float* __restrict__ x,
                                              const float* __restrict__ W1,
                                              int* __restrict__ rowBeg,
                                              int* __restrict__ rowEnd,
                                              float* __restrict__ dinv,
                                              int* __restrict__ srcSorted,
                                              __half* __restrict__ p1) {
    __shared__ int cnt[BK];
    __shared__ int scn[BK];
    __shared__ int cur[BK];
    __shared__ float sW[1024];
    int t = threadIdx.x;
    int b = blockIdx.x;
    int c = b >> 4;                 // parent coarse bucket
    unsigned fl = (unsigned)(b & 15);  // fine index within coarse
    int seg0 = c * CAPC;
    int cc = cursor1[c] - seg0; if (cc > CAPC) cc = CAPC;
    int segEnd = seg0 + cc;
    if (t < BK) cnt[t] = 0;
    for (int i = t; i < 1024; i += 256) sW[i] = W1[i];
    __syncthreads();
    // phase 1: filtered histogram of this fine bucket's 64 nodes
    for (int i = seg0 + t; i < segEnd; i += 256) {
        unsigned dl = packed1[i] >> 17;
        if ((dl >> 6) == fl) atomicAdd(&cnt[dl & 63u], 1);
    }
    __syncthreads();
    // phase 2: local exclusive scan (64 wide) -> rowBeg/rowEnd/dinv
    int v = (t < BK) ? cnt[t] : 0;
    if (t < BK) scn[t] = v;
    __syncthreads();
    for (int off = 1; off < BK; off <<= 1) {
        int u = (t < BK && t >= off) ? scn[t - off] : 0;
        __syncthreads();
        if (t < BK) scn[t] += u;
        __syncthreads();
    }
    int fseg0 = b * CAPF;
    int node = b * BK + t;
    if (t < BK) {
        int start = fseg0 + scn[t] - v;
        if (node < N_NODES) {
            rowBeg[node] = start;
            rowEnd[node] = start + v;
            dinv[node] = rsqrtf((float)(v + 1));   // +1 = self loop
        }
        cur[t] = start;
    }
    __syncthreads();
    // phase 3a: filtered placement into srcSorted (L2-hot second scan)
    for (int i = seg0 + t; i < segEnd; i += 256) {
        unsigned pk = packed1[i];
        unsigned dl = pk >> 17;
        if ((dl >> 6) == fl) {
            int pos = atomicAdd(&cur[dl & 63u], 1);
            if (pos < (b + 1) * CAPF)   // impossible-overflow guard
                srcSorted[pos] = (int)(pk & 0x1FFFFu);
        }
    }
    // phase 3b: p1 = dinv * (x @ W1) for this block's 64 nodes (+ sentinel)
    int lane = t & 31;
    for (int r = (t >> 5); r < BK; r += 8) {
        int nd = b * BK + r;
        if (nd > N_NODES) break;
        if (nd == N_NODES) {                      // sentinel zero row
            p1[nd * 32 + lane] = __float2half(0.f);
            continue;
        }
        float xv = x[nd * 32 + lane];
        float a = 0.f;
#pragma unroll
        for (int k = 0; k < 32; ++k) {
            float xk = __shfl(xv, k, 32);
            a += xk * sW[k * 32 + lane];
        }
        float di = rsqrtf((float)(cnt[r] + 1));
        p1[nd * 32 + lane] = __float2half(di * a);
    }
}

// ---------------- gather layer 1 + relu + layer-2 matmul (4 lanes/node) --------
__global__ __launch_bounds__(256) void k_gx2(const int* __restrict__ rowBeg,
                                             const int* __restrict__ rowEnd,
                                             const int* __restrict__ srcSorted,
                                             const __half* __restrict__ p1,
                                             const float* __restrict__ dinv,
                                             const float* __restrict__ b1,
                                             const float* __restrict__ Wmu,
                                             const float* __restrict__ Wlv,
                                             __half* __restrict__ p2) {
    __shared__ float sW[1024];       // [k][oc], oc: 0-15 mu, 16-31 lv
    __shared__ float sB[32];
    int t = threadIdx.x;
    for (int i = t; i < 1024; i += 256) {
        int k = i >> 5, oc = i & 31;
        sW[i] = (oc < 16) ? Wmu[k * 16 + oc] : Wlv[k * 16 + (oc - 16)];
    }
    if (t < 32) sB[t] = b1[t];
    __syncthreads();
    int l = t & 3;
    int node = blockIdx.x * 64 + (t >> 2);   // 1563*64 covers N + sentinel
    if (node > N_NODES) return;
    const float4* P = (const float4*)p1;
    if (node == N_NODES) {                   // sentinel zero row of p2
        ((float4*)p2)[node * 4 + l] = make_float4(0.f, 0.f, 0.f, 0.f);
        return;
    }
    float acc[8] = {0.f, 0.f, 0.f, 0.f, 0.f, 0.f, 0.f, 0.f};
    gatherRow4(srcSorted, P, rowBeg[node], rowEnd[node], l, acc);
    float di = dinv[node];
    float4 ps = P[node * 4 + l];             // self loop analytic
    float h[8];
#pragma unroll
    for (int c = 0; c < 4; ++c) {
        float2 f = __half22float2(h2of(ps, c));
        h[2 * c]     = fmaxf(di * (acc[2 * c]     + f.x) + sB[8 * l + 2 * c],     0.f);
        h[2 * c + 1] = fmaxf(di * (acc[2 * c + 1] + f.y) + sB[8 * l + 2 * c + 1], 0.f);
    }
    float o[8] = {0.f, 0.f, 0.f, 0.f, 0.f, 0.f, 0.f, 0.f};
    const float4* W4 = (const float4*)sW;
#pragma unroll
    for (int m = 0; m < 4; ++m) {
#pragma unroll
        for (int j = 0; j < 8; ++j) {
            float hk = __shfl(h[j], m, 4);   // channel k = 8m+j
            int k = 8 * m + j;
            float4 wa = W4[k * 8 + 2 * l];
            float4 wb = W4[k * 8 + 2 * l + 1];
            o[0] += hk * wa.x; o[1] += hk * wa.y; o[2] += hk * wa.z; o[3] += hk * wa.w;
            o[4] += hk * wb.x; o[5] += hk * wb.y; o[6] += hk * wb.z; o[7] += hk * wb.w;
        }
    }
    __half2 r0 = __floats2half2_rn(di * o[0], di * o[1]);
    __half2 r1 = __floats2half2_rn(di * o[2], di * o[3]);
    __half2 r2 = __floats2half2_rn(di * o[4], di * o[5]);
    __half2 r3 = __floats2half2_rn(di * o[6], di * o[7]);
    float4 st;
    st.x = *reinterpret_cast<float*>(&r0);
    st.y = *reinterpret_cast<float*>(&r1);
    st.z = *reinterpret_cast<float*>(&r2);
    st.w = *reinterpret_cast<float*>(&r3);
    ((float4*)p2)[node * 4 + l] = st;
}

// ---------------- gather layer 2 + mu/logvar epilogue (4 lanes/node) ----------
__global__ __launch_bounds__(256) void k_gfin(const int* __restrict__ rowBeg,
                                              const int* __restrict__ rowEnd,
                                              const int* __restrict__ srcSorted,
                                              const __half* __restrict__ p2,
                                              const float* __restrict__ dinv,
                                              const float* __restrict__ bmu,
                                              const float* __restrict__ blv,
                                              float* __restrict__ out) {
    __shared__ float sB[32];
    int t = threadIdx.x;
    if (t < 32) sB[t] = (t < 16) ? bmu[t] : blv[t - 16];
    __syncthreads();
    int l = t & 3;
    int node = blockIdx.x * 64 + (t >> 2);
    if (node >= N_NODES) return;
    const float4* P = (const float4*)p2;
    float acc[8] = {0.f, 0.f, 0.f, 0.f, 0.f, 0.f, 0.f, 0.f};
    gatherRow4(srcSorted, P, rowBeg[node], rowEnd[node], l, acc);
    float di = dinv[node];
    float4 ps = P[node * 4 + l];
    float v[8];
#pragma unroll
    for (int c = 0; c < 4; ++c) {
        float2 f = __half22float2(h2of(ps, c));
        v[2 * c]     = di * (acc[2 * c]     + f.x) + sB[8 * l + 2 * c];
        v[2 * c + 1] = di * (acc[2 * c + 1] + f.y) + sB[8 * l + 2 * c + 1];
    }
    float4 o0 = make_float4(v[0], v[1], v[2], v[3]);
    float4 o1 = make_float4(v[4], v[5], v[6], v[7]);
    float4* dst4 = (l < 2) ? (float4*)out
                           : (float4*)(out + (size_t)N_NODES * 16);
    int b4 = node * 4 + (l & 1) * 2;
    dst4[b4]     = o0;
    dst4[b4 + 1] = o1;
}

extern "C" void kernel_launch(void* const* d_in, const int* in_sizes, int n_in,
                              void* d_out, int out_size, void* d_ws, size_t ws_size,
                              hipStream_t stream) {
    const float* x   = (const float*)d_in[0];
    const int*   ei  = (const int*)d_in[1];
    const float* W1  = (const float*)d_in[2];
    const float* b1  = (const float*)d_in[3];
    const float* Wmu = (const float*)d_in[4];
    const float* bmu = (const float*)d_in[5];
    const float* Wlv = (const float*)d_in[6];
    const float* blv = (const float*)d_in[7];
    float* out = (float*)d_out;

    const int* src = ei;            // edge_index[0]
    const int* dst = ei + N_EDGES;  // edge_index[1]

    // workspace (4B units), 256B-aligned big buffers for float4 access:
    //  cursor1[98] | rowBeg[N] | rowEnd[N] | dinv[N] | pad
    //  | packed1[98*17500 = 6.9MB]  (aliased by p2h after k_csrx)
    //  | srcSorted[1563*1408 = 8.8MB]
    //  | p1h[(N+1)*32 halves = 6.4MB]  (own storage: csrx reads packed1
    //                                   while writing p1 -> no alias)
    // Total ~23.3 MB.
    size_t off = 0;
    int* cursor1 = (int*)d_ws;                          off += NCB;
    int* rowBeg  = (int*)d_ws + off;                    off += N_NODES;
    int* rowEnd  = (int*)d_ws + off;                    off += N_NODES;
    float* dinv  = (float*)((int*)d_ws + off);          off += N_NODES;
    off = (off + 63) & ~(size_t)63;                     // 256B align
    unsigned* packed1 = (unsigned*)((int*)d_ws + off);  off += (size_t)NCB * CAPC;
    off = (off + 63) & ~(size_t)63;
    int* srcSorted    = (int*)d_ws + off;               off += (size_t)NBF * CAPF;
    off = (off + 63) & ~(size_t)63;
    __half* p1h       = (__half*)((int*)d_ws + off);
    __half* p2h       = (__half*)packed1;  // alias: packed1 dead after k_csrx

    k_binit<<<1, 128, 0, stream>>>(cursor1);
    k_part1<<<NCH, 256, 0, stream>>>(src, dst, cursor1, packed1);
    k_csrx <<<NBF, 256, 0, stream>>>(packed1, cursor1, x, W1,
                                     rowBeg, rowEnd, dinv, srcSorted, p1h);
    k_gx2  <<<NBF, 256, 0, stream>>>(rowBeg, rowEnd, srcSorted, p1h, dinv,
                                     b1, Wmu, Wlv, p2h);
    k_gfin <<<NBF, 256, 0, stream>>>(rowBeg, rowEnd, srcSorted, p2h, dinv,
                                     bmu, blv, out);
}

// Round 15
// 189.890 us; speedup vs baseline: 3.2569x; 1.1935x over previous
//
#include <hip/hip_runtime.h>
#include <hip/hip_fp16.h>

#define N_NODES 100000
#define N_EDGES 1600000
// coarse buckets (partition pass 1): 1024 nodes, bucket = dst >> 10
#define NCB 98
#define CAPC 17500          // mean 16327, sigma ~127 -> +9 sigma
#define P1_CHUNK 4096
#define P1_BLOCKS 391       // ceil(E/4096)
// fine buckets (partition pass 2 / CSR): 64 nodes, 16 fines per coarse
#define BK 64
#define NBF 1563            // ceil(N/64)
#define CAPF 1408           // mean 1024, sigma ~32 -> +12 sigma
#define P2_SPLIT 16         // blocks per coarse bucket

// cursors are COUNTS (0-initialized via hipMemsetAsync); absolute position =
// bucket*CAP + relative offset.

// ---------------- pass 1: partition edges into 98 coarse buckets ----------------
// packed1 entry: (dstLow10 << 17) | src17
__global__ __launch_bounds__(512) void k_part1(const int* __restrict__ src,
                                               const int* __restrict__ dst,
                                               int* __restrict__ cursor1,
                                               unsigned* __restrict__ packed1) {
    __shared__ int bh[NCB];
    __shared__ int base[NCB];
    int t = threadIdx.x;
    if (t < NCB) bh[t] = 0;
    __syncthreads();
    int e0 = blockIdx.x * P1_CHUNK;
    int e1 = e0 + P1_CHUNK; if (e1 > N_EDGES) e1 = N_EDGES;
    for (int e = e0 + t; e < e1; e += 512)
        atomicAdd(&bh[((unsigned)dst[e]) >> 10], 1);
    __syncthreads();
    if (t < NCB) {
        int c = bh[t];
        base[t] = t * CAPC + ((c > 0) ? atomicAdd(&cursor1[t], c) : 0);
        bh[t] = 0;   // reuse as rank counter
    }
    __syncthreads();
    for (int e = e0 + t; e < e1; e += 512) {
        unsigned d = (unsigned)dst[e];
        int b = d >> 10;
        int r = atomicAdd(&bh[b], 1);
        int pos = base[b] + r;
        if (pos < (b + 1) * CAPC)   // statistically impossible overflow guard
            packed1[pos] = ((d & 1023u) << 17) | (unsigned)src[e];
    }
}

// ---------------- pass 2: refine coarse -> 16 fine buckets, coalesced writes ----
// packed2 entry: (dstLow6 << 17) | src17
__global__ __launch_bounds__(256) void k_part2(const unsigned* __restrict__ packed1,
                                               const int* __restrict__ cursor1,
                                               int* __restrict__ cursor2,
                                               unsigned* __restrict__ packed2) {
    __shared__ int bh[16];
    __shared__ int base[16];
    int t = threadIdx.x;
    int c = blockIdx.x / P2_SPLIT;
    int k = blockIdx.x % P2_SPLIT;
    int cc = cursor1[c]; if (cc > CAPC) cc = CAPC;
    int s0 = c * CAPC + (k * cc) / P2_SPLIT;
    int s1 = c * CAPC + ((k + 1) * cc) / P2_SPLIT;
    if (t < 16) bh[t] = 0;
    __syncthreads();
    for (int i = s0 + t; i < s1; i += 256)
        atomicAdd(&bh[(packed1[i] >> 17) >> 6], 1);
    __syncthreads();
    if (t < 16) {
        int cnt = bh[t];
        int fb = c * 16 + t;   // fb >= NBF only possible with cnt==0 (tail coarse)
        base[t] = fb * CAPF + ((cnt > 0) ? atomicAdd(&cursor2[fb], cnt) : 0);
        bh[t] = 0;   // reuse as rank counter
    }
    __syncthreads();
    for (int i = s0 + t; i < s1; i += 256) {
        unsigned pk = packed1[i];
        unsigned dl = pk >> 17;          // 10-bit dstLow
        int f = dl >> 6;
        int r = atomicAdd(&bh[f], 1);
        int pos = base[f] + r;
        int fb = c * 16 + f;
        if (pos < (fb + 1) * CAPF)
            packed2[pos] = ((dl & 63u) << 17) | (pk & 0x1FFFFu);
    }
}

// ---------------- fused: per-fine-bucket CSR build + dinv + p1 = dinv*(x@W1) ----
// Also writes the sentinel zero row p1[N_NODES] (used by gather tail padding).
__global__ __launch_bounds__(256) void k_csrx(const unsigned* __restrict__ packed2,
                                              const int* __restrict__ cursor2,
                                              const float* __restrict__ x,
                                              const float* __restrict__ W1,
                                              int* __restrict__ rowBeg,
                                              int* __restrict__ rowEnd,
                                              float* __restrict__ dinv,
                                              int* __restrict__ srcSorted,
                                              __half* __restrict__ p1) {
    __shared__ int cnt[BK];
    __shared__ int scn[BK];
    __shared__ int cur[BK];
    __shared__ float sW[1024];
    int t = threadIdx.x;
    int b = blockIdx.x;
    int seg0 = b * CAPF;
    int cc = cursor2[b]; if (cc > CAPF) cc = CAPF;
    int segEnd = seg0 + cc;
    if (t < BK) cnt[t] = 0;
    for (int i = t; i < 1024; i += 256) sW[i] = W1[i];
    __syncthreads();
    // phase 1: per-node histogram
    for (int i = seg0 + t; i < segEnd; i += 256)
        atomicAdd(&cnt[packed2[i] >> 17], 1);
    __syncthreads();
    // phase 2: local exclusive scan (64 wide) -> rowBeg/rowEnd/dinv
    int v = (t < BK) ? cnt[t] : 0;
    if (t < BK) scn[t] = v;
    __syncthreads();
    for (int off = 1; off < BK; off <<= 1) {
        int u = (t < BK && t >= off) ? scn[t - off] : 0;
        __syncthreads();
        if (t < BK) scn[t] += u;
        __syncthreads();
    }
    int node = b * BK + t;
    if (t < BK) {
        int start = seg0 + scn[t] - v;
        if (node < N_NODES) {
            rowBeg[node] = start;
            rowEnd[node] = start + v;
            dinv[node] = rsqrtf((float)(v + 1));   // +1 = self loop
        }
        cur[t] = start;
    }
    __syncthreads();
    // phase 3a: fill srcSorted
    for (int i = seg0 + t; i < segEnd; i += 256) {
        unsigned pk = packed2[i];
        int pos = atomicAdd(&cur[pk >> 17], 1);
        srcSorted[pos] = (int)(pk & 0x1FFFFu);
    }
    // phase 3b: p1 = dinv * (x @ W1) for this block's 64 nodes (+ sentinel)
    int lane = t & 31;
    for (int r = (t >> 5); r < BK; r += 8) {
        int nd = b * BK + r;
        if (nd > N_NODES) break;
        if (nd == N_NODES) {                      // sentinel zero row
            p1[nd * 32 + lane] = __float2half(0.f);
            continue;
        }
        float xv = x[nd * 32 + lane];
        float a = 0.f;
#pragma unroll
        for (int k = 0; k < 32; ++k) {
            float xk = __shfl(xv, k, 32);
            a += xk * sW[k * 32 + lane];
        }
        float di = rsqrtf((float)(cnt[r] + 1));
        p1[nd * 32 + lane] = __float2half(di * a);
    }
}

// ---------------- 4-lane gather: lane owns channels 8l..8l+7, 16B loads --------
// One VMEM instr covers 16 edges/wave. Tail edges load the sentinel zero row
// (index N_NODES) instead of branching. fp16 8-term tree partials -> fp32 flush.
__device__ __forceinline__ __half2 h2of(const float4& v, int c) {
    return reinterpret_cast<const __half2*>(&v)[c];
}

__device__ __forceinline__ void gatherRow4(const int* __restrict__ srcSorted,
                                           const float4* __restrict__ P,
                                           int beg, int end, int l,
                                           float* __restrict__ acc /*[8]*/) {
    for (int base = beg; base < end; base += 8) {
        int i0 = base + l, i1 = base + 4 + l;
        int sA = (i0 < end) ? srcSorted[i0] : N_NODES;
        int sB = (i1 < end) ? srcSorted[i1] : N_NODES;
        float4 v0 = P[__shfl(sA, 0, 4) * 4 + l];
        float4 v1 = P[__shfl(sA, 1, 4) * 4 + l];
        float4 v2 = P[__shfl(sA, 2, 4) * 4 + l];
        float4 v3 = P[__shfl(sA, 3, 4) * 4 + l];
        float4 v4 = P[__shfl(sB, 0, 4) * 4 + l];
        float4 v5 = P[__shfl(sB, 1, 4) * 4 + l];
        float4 v6 = P[__shfl(sB, 2, 4) * 4 + l];
        float4 v7 = P[__shfl(sB, 3, 4) * 4 + l];
#pragma unroll
        for (int c = 0; c < 4; ++c) {
            __half2 s01 = __hadd2(h2of(v0, c), h2of(v1, c));
            __half2 s23 = __hadd2(h2of(v2, c), h2of(v3, c));
            __half2 s45 = __hadd2(h2of(v4, c), h2of(v5, c));
            __half2 s67 = __hadd2(h2of(v6, c), h2of(v7, c));
            __half2 sum = __hadd2(__hadd2(s01, s23), __hadd2(s45, s67));
            float2 f = __half22float2(sum);
            acc[2 * c]     += f.x;
            acc[2 * c + 1] += f.y;
        }
    }
}

// ---------------- gather layer 1 + relu + layer-2 matmul (4 lanes/node) --------
__global__ __launch_bounds__(256) void k_gx2(const int* __restrict__ rowBeg,
                                             const int* __restrict__ rowEnd,
                                             const int* __restrict__ srcSorted,
                                             const __half* __restrict__ p1,
                                             const float* __restrict__ dinv,
                                             const float* __restrict__ b1,
                                             const float* __restrict__ Wmu,
                                             const float* __restrict__ Wlv,
                                             __half* __restrict__ p2) {
    __shared__ float sW[1024];       // [k][oc], oc: 0-15 mu, 16-31 lv
    __shared__ float sB[32];
    int t = threadIdx.x;
    for (int i = t; i < 1024; i += 256) {
        int k = i >> 5, oc = i & 31;
        sW[i] = (oc < 16) ? Wmu[k * 16 + oc] : Wlv[k * 16 + (oc - 16)];
    }
    if (t < 32) sB[t] = b1[t];
    __syncthreads();
    int l = t & 3;
    int node = blockIdx.x * 64 + (t >> 2);   // 1563*64 covers N + sentinel
    if (node > N_NODES) return;
    const float4* P = (const float4*)p1;
    if (node == N_NODES) {                   // sentinel zero row of p2
        ((float4*)p2)[node * 4 + l] = make_float4(0.f, 0.f, 0.f, 0.f);
        return;
    }
    float acc[8] = {0.f, 0.f, 0.f, 0.f, 0.f, 0.f, 0.f, 0.f};
    gatherRow4(srcSorted, P, rowBeg[node], rowEnd[node], l, acc);
    float di = dinv[node];
    float4 ps = P[node * 4 + l];             // self loop analytic
    float h[8];
#pragma unroll
    for (int c = 0; c < 4; ++c) {
        float2 f = __half22float2(h2of(ps, c));
        h[2 * c]     = fmaxf(di * (acc[2 * c]     + f.x) + sB[8 * l + 2 * c],     0.f);
        h[2 * c + 1] = fmaxf(di * (acc[2 * c + 1] + f.y) + sB[8 * l + 2 * c + 1], 0.f);
    }
    float o[8] = {0.f, 0.f, 0.f, 0.f, 0.f, 0.f, 0.f, 0.f};
    const float4* W4 = (const float4*)sW;
#pragma unroll
    for (int m = 0; m < 4; ++m) {
#pragma unroll
        for (int j = 0; j < 8; ++j) {
            float hk = __shfl(h[j], m, 4);   // channel k = 8m+j
            int k = 8 * m + j;
            float4 wa = W4[k * 8 + 2 * l];
            float4 wb = W4[k * 8 + 2 * l + 1];
            o[0] += hk * wa.x; o[1] += hk * wa.y; o[2] += hk * wa.z; o[3] += hk * wa.w;
            o[4] += hk * wb.x; o[5] += hk * wb.y; o[6] += hk * wb.z; o[7] += hk * wb.w;
        }
    }
    __half2 r0 = __floats2half2_rn(di * o[0], di * o[1]);
    __half2 r1 = __floats2half2_rn(di * o[2], di * o[3]);
    __half2 r2 = __floats2half2_rn(di * o[4], di * o[5]);
    __half2 r3 = __floats2half2_rn(di * o[6], di * o[7]);
    float4 st;
    st.x = *reinterpret_cast<float*>(&r0);
    st.y = *reinterpret_cast<float*>(&r1);
    st.z = *reinterpret_cast<float*>(&r2);
    st.w = *reinterpret_cast<float*>(&r3);
    ((float4*)p2)[node * 4 + l] = st;
}

// ---------------- gather layer 2 + mu/logvar epilogue (4 lanes/node) ----------
__global__ __launch_bounds__(256) void k_gfin(const int* __restrict__ rowBeg,
                                              const int* __restrict__ rowEnd,
                                              const int* __restrict__ srcSorted,
                                              const __half* __restrict__ p2,
                                              const float* __restrict__ dinv,
                                              const float* __restrict__ bmu,
                                              const float* __restrict__ blv,
                                              float* __restrict__ out) {
    __shared__ float sB[32];
    int t = threadIdx.x;
    if (t < 32) sB[t] = (t < 16) ? bmu[t] : blv[t - 16];
    __syncthreads();
    int l = t & 3;
    int node = blockIdx.x * 64 + (t >> 2);
    if (node >= N_NODES) return;
    const float4* P = (const float4*)p2;
    float acc[8] = {0.f, 0.f, 0.f, 0.f, 0.f, 0.f, 0.f, 0.f};
    gatherRow4(srcSorted, P, rowBeg[node], rowEnd[node], l, acc);
    float di = dinv[node];
    float4 ps = P[node * 4 + l];
    float v[8];
#pragma unroll
    for (int c = 0; c < 4; ++c) {
        float2 f = __half22float2(h2of(ps, c));
        v[2 * c]     = di * (acc[2 * c]     + f.x) + sB[8 * l + 2 * c];
        v[2 * c + 1] = di * (acc[2 * c + 1] + f.y) + sB[8 * l + 2 * c + 1];
    }
    float4 o0 = make_float4(v[0], v[1], v[2], v[3]);
    float4 o1 = make_float4(v[4], v[5], v[6], v[7]);
    float4* dst4 = (l < 2) ? (float4*)out
                           : (float4*)(out + (size_t)N_NODES * 16);
    int b4 = node * 4 + (l & 1) * 2;
    dst4[b4]     = o0;
    dst4[b4 + 1] = o1;
}

extern "C" void kernel_launch(void* const* d_in, const int* in_sizes, int n_in,
                              void* d_out, int out_size, void* d_ws, size_t ws_size,
                              hipStream_t stream) {
    const float* x   = (const float*)d_in[0];
    const int*   ei  = (const int*)d_in[1];
    const float* W1  = (const float*)d_in[2];
    const float* b1  = (const float*)d_in[3];
    const float* Wmu = (const float*)d_in[4];
    const float* bmu = (const float*)d_in[5];
    const float* Wlv = (const float*)d_in[6];
    const float* blv = (const float*)d_in[7];
    float* out = (float*)d_out;

    const int* src = ei;            // edge_index[0]
    const int* dst = ei + N_EDGES;  // edge_index[1]

    // workspace (4B units), 256B-aligned big buffers for float4 access:
    //  cursor1[98] | cursor2[1563]  (COUNTS, zeroed by memset below)
    //  | rowBeg[N] | rowEnd[N] | dinv[N] | pad
    //  | packed1[98*17500]  (aliased by p1h incl. sentinel row)
    //  | packed2[1563*1408] (aliased by p2h incl. sentinel row)
    //  | srcSorted[1563*1408]
    size_t off = 0;
    int* cursor1 = (int*)d_ws;                          off += NCB;
    int* cursor2 = (int*)d_ws + off;                    off += NBF;
    int* rowBeg  = (int*)d_ws + off;                    off += N_NODES;
    int* rowEnd  = (int*)d_ws + off;                    off += N_NODES;
    float* dinv  = (float*)((int*)d_ws + off);          off += N_NODES;
    off = (off + 63) & ~(size_t)63;                     // 256B align
    unsigned* packed1 = (unsigned*)((int*)d_ws + off);  off += (size_t)NCB * CAPC;
    off = (off + 63) & ~(size_t)63;
    unsigned* packed2 = (unsigned*)((int*)d_ws + off);  off += (size_t)NBF * CAPF;
    off = (off + 63) & ~(size_t)63;
    int* srcSorted    = (int*)d_ws + off;
    __half* p1h       = (__half*)packed1;  // alias: packed1 dead after k_part2
    __half* p2h       = (__half*)packed2;  // alias: packed2 dead after k_csrx

    // cursor init: counts-relative cursors -> plain zeroing (capture-legal)
    hipMemsetAsync(d_ws, 0, (size_t)(NCB + NBF) * sizeof(int), stream);
    k_part1<<<P1_BLOCKS, 512, 0, stream>>>(src, dst, cursor1, packed1);
    k_part2<<<NCB * P2_SPLIT, 256, 0, stream>>>(packed1, cursor1, cursor2, packed2);
    k_csrx <<<NBF, 256, 0, stream>>>(packed2, cursor2, x, W1,
                                     rowBeg, rowEnd, dinv, srcSorted, p1h);
    k_gx2  <<<NBF, 256, 0, stream>>>(rowBeg, rowEnd, srcSorted, p1h, dinv,
                                     b1, Wmu, Wlv, p2h);
    k_gfin <<<NBF, 256, 0, stream>>>(rowBeg, rowEnd, srcSorted, p2h, dinv,
                                     bmu, blv, out);
}